// Round 10
// baseline (694.188 us; speedup 1.0000x reference)
//
#include <hip/hip_runtime.h>
#include <hip/hip_bf16.h>

// N_NODES=50000, N_EDGES=800000, C_IN=64, N_HEADS=4, HEAD_DIM=16, FC=64
// R9: counting-sort edges by dst; edge kernel processes edges in sorted order
// and MERGES equal-dst contributions in registers before atomics (segmented
// emit) -> ~3-4x fewer device-scope f32 atomic ops (the R8-identified wall).

typedef __attribute__((ext_vector_type(8))) short    bf16x8;
typedef __attribute__((ext_vector_type(4))) float    f32x4;
typedef __attribute__((ext_vector_type(4))) unsigned short ushort4v;

__device__ __forceinline__ unsigned short f2bf(float x) {
    union { float f; unsigned u; } v; v.f = x;
    unsigned r = v.u + 0x7fffu + ((v.u >> 16) & 1u);   // round-to-nearest-even
    return (unsigned short)(r >> 16);
}

// swizzled ushort index for a [*][64]-bf16 LDS tile (T2 XOR swizzle)
__device__ __forceinline__ int swz(int row, int k) {
    return row * 64 + (k ^ ((row & 7) << 3));
}

// MFMA fragment load: 8 contiguous bf16 at (row|n, k = kk*32 + lhi*8)
__device__ __forceinline__ bf16x8 ldfrag(const unsigned short* buf, int rn, int kk, int lhi) {
    return *(const bf16x8*)(buf + swz(rn, kk * 32 + lhi * 8));
}

#define PHASE_FENCE() asm volatile("" ::: "memory")

// ---------------------------------------------------------------------------
// Sort kernels: counting sort of edges by dst.
// ---------------------------------------------------------------------------
__global__ __launch_bounds__(256)
void hist_kernel(const int* __restrict__ edst, int* __restrict__ cnt, int E)
{
    const int e = blockIdx.x * 256 + threadIdx.x;
    if (e < E) atomicAdd(&cnt[edst[e]], 1);
}

// single-block exclusive scan: cursor[i] = sum_{j<i} cnt[j]
__global__ __launch_bounds__(1024)
void scan_kernel(const int* __restrict__ cnt, int* __restrict__ cursor, int N)
{
    __shared__ int wsum[16];
    const int t = threadIdx.x;
    const int lane = t & 63, wv = t >> 6;
    const int CH = (N + 1023) / 1024;
    const int lo = t * CH;
    const int hi = (lo + CH < N) ? lo + CH : N;
    int s = 0;
    for (int i = lo; i < hi; ++i) s += cnt[i];
    int x = s;                                  // wave inclusive scan
    for (int off = 1; off < 64; off <<= 1) {
        int y = __shfl_up(x, off);
        if (lane >= off) x += y;
    }
    if (lane == 63) wsum[wv] = x;
    __syncthreads();
    if (wv == 0 && lane < 16) {
        int w = wsum[lane];
        for (int off = 1; off < 16; off <<= 1) {
            int y = __shfl_up(w, off);
            if (lane >= off) w += y;
        }
        wsum[lane] = w;                         // inclusive wave prefix
    }
    __syncthreads();
    int base = (wv > 0 ? wsum[wv - 1] : 0) + (x - s);   // exclusive offset
    for (int i = lo; i < hi; ++i) { cursor[i] = base; base += cnt[i]; }
}

__global__ __launch_bounds__(256)
void rank_kernel(const int* __restrict__ edst, int* __restrict__ cursor,
                 int* __restrict__ perm, int E)
{
    const int e = blockIdx.x * 256 + threadIdx.x;
    if (e < E) {
        const int p = atomicAdd(&cursor[edst[e]], 1);
        perm[p] = e;
    }
}

// ---------------------------------------------------------------------------
// Kernel P: one-time weight conversion to bf16, PRE-SWIZZLED, into d_ws.
// ---------------------------------------------------------------------------
__global__ __launch_bounds__(256)
void prep_weights(const float* __restrict__ W1, const float* __restrict__ W2,
                  const float* __restrict__ W3, const float* __restrict__ Wkv,
                  unsigned short* __restrict__ wbf)
{
    const int d = blockIdx.x * 256 + threadIdx.x;      // 0..20479
    if (d < 12288) {
        const int w  = d >> 12;
        const int r  = d & 4095;
        const int n  = r >> 6, kx = r & 63;
        const int k  = kx ^ ((n & 7) << 3);
        const float* W = (w == 0) ? W1 : (w == 1) ? W2 : W3;
        wbf[d] = f2bf(W[k * 64 + n]);
    } else if (d < 20480) {
        const int r  = d - 12288;
        const int n  = r >> 6, kx = r & 63;             // n: 0..127
        const int k  = kx ^ ((n & 7) << 3);
        wbf[d] = f2bf(Wkv[k * 128 + n]);
    }
}

// ---------------------------------------------------------------------------
// Kernel A: node-side linears, persistent (unchanged).
// ---------------------------------------------------------------------------
__global__ __launch_bounds__(384)
void node_linear_kernel(const float* __restrict__ x,
                        const float* __restrict__ Wq,   const float* __restrict__ bq,
                        const float* __restrict__ Wsrc, const float* __restrict__ bsrc,
                        const float* __restrict__ Wdst,
                        float* __restrict__ qout, float* __restrict__ msout,
                        float* __restrict__ mdout, int N, int ntiles)
{
    __shared__ __align__(16) float sW[64 * 192];
    __shared__ float sb[192];
    __shared__ __align__(16) float xs[32][68];

    const int t = threadIdx.x;
    for (int idx4 = t; idx4 < 3072; idx4 += 384) {
        const int k  = idx4 / 48;
        const int j4 = idx4 % 48;
        const float4* src = (j4 < 16) ? (const float4*)&Wq  [k * 64 + j4 * 4]
                         : (j4 < 32) ? (const float4*)&Wsrc[k * 64 + (j4 - 16) * 4]
                                     : (const float4*)&Wdst[k * 64 + (j4 - 32) * 4];
        ((float4*)sW)[idx4] = *src;
    }
    if (t < 192) sb[t] = (t < 64) ? bq[t] : (t < 128) ? bsrc[t - 64] : 0.0f;

    const int te = t / 48, tj = t % 48;
    const int j0 = tj * 4, e0 = te * 4;

    for (int tile = blockIdx.x; tile < ntiles; tile += gridDim.x) {
        const int nbase = tile * 32;
        __syncthreads();
        for (int idx = t; idx < 512; idx += 384) {
            const int n  = idx >> 4;
            const int c4 = (idx & 15) * 4;
            const int gn = nbase + n;
            float4 g = make_float4(0.f, 0.f, 0.f, 0.f);
            if (gn < N) g = *(const float4*)&x[(size_t)gn * 64 + c4];
            *(float4*)&xs[n][c4] = g;
        }
        __syncthreads();

        float acc[4][4];
#pragma unroll
        for (int i = 0; i < 4; ++i)
#pragma unroll
            for (int c = 0; c < 4; ++c) acc[i][c] = 0.f;

#pragma unroll 16
        for (int k = 0; k < 64; ++k) {
            const float4 wv = *(const float4*)&sW[k * 192 + j0];
            const float a0 = xs[e0 + 0][k], a1 = xs[e0 + 1][k];
            const float a2 = xs[e0 + 2][k], a3 = xs[e0 + 3][k];
            acc[0][0] += a0 * wv.x; acc[0][1] += a0 * wv.y; acc[0][2] += a0 * wv.z; acc[0][3] += a0 * wv.w;
            acc[1][0] += a1 * wv.x; acc[1][1] += a1 * wv.y; acc[1][2] += a1 * wv.z; acc[1][3] += a1 * wv.w;
            acc[2][0] += a2 * wv.x; acc[2][1] += a2 * wv.y; acc[2][2] += a2 * wv.z; acc[2][3] += a2 * wv.w;
            acc[3][0] += a3 * wv.x; acc[3][1] += a3 * wv.y; acc[3][2] += a3 * wv.z; acc[3][3] += a3 * wv.w;
        }

#pragma unroll
        for (int i = 0; i < 4; ++i) {
            const int gn = nbase + e0 + i;
            if (gn >= N) continue;
            float4 o;
            o.x = acc[i][0] + sb[j0 + 0];
            o.y = acc[i][1] + sb[j0 + 1];
            o.z = acc[i][2] + sb[j0 + 2];
            o.w = acc[i][3] + sb[j0 + 3];
            if (j0 < 64) {
                o.x *= 0.25f; o.y *= 0.25f; o.z *= 0.25f; o.w *= 0.25f;
                *(float4*)&qout[(size_t)gn * 64 + j0] = o;
            } else if (j0 < 128) {
                *(float4*)&msout[(size_t)gn * 64 + (j0 - 64)] = o;
            } else {
                *(float4*)&mdout[(size_t)gn * 64 + (j0 - 128)] = o;
            }
        }
    }
}

// ---------------------------------------------------------------------------
// Kernel B (MFMA): fused per-edge chain over DST-SORTED edges (via perm),
// persistent, barrier-free main loop, register-merged segmented atomics.
// ---------------------------------------------------------------------------
__global__ __launch_bounds__(512, 4)
void edge_fused_mfma(const int* __restrict__ esrc, const int* __restrict__ edst,
                     const float* __restrict__ eattr, const float* __restrict__ escal,
                     const int* __restrict__ perm,
                     const unsigned short* __restrict__ wbf,
                     const float* __restrict__ b1, const float* __restrict__ b2,
                     const float* __restrict__ b3, const float* __restrict__ bkv,
                     const float* __restrict__ qbuf, const float* __restrict__ msrc,
                     const float* __restrict__ mdst,
                     float* __restrict__ num, float* __restrict__ den, int ntiles)
{
    __shared__ __align__(16) unsigned short sh[36864];  // 73728 B
    unsigned short* sW1t  = sh;           // [64][64] bf16, transposed+swz
    unsigned short* sW2t  = sh + 4096;
    unsigned short* sW3t  = sh + 8192;
    unsigned short* sWkvt = sh + 12288;   // [128][64]
    unsigned short* sA0   = sh + 20480;   // [128 edges][64] act ping (wave-private rows)
    unsigned short* sA1   = sh + 28672;   // act pong
    __shared__ float sB1[64], sB2[64], sB3[64], sBkv[128];

    const int t    = threadIdx.x;
    const int lane = t & 63;
    const int wave = t >> 6;
    const int l15  = lane & 15;
    const int lhi  = lane >> 4;          // 0..3
    const int rowBase = wave * 16;
    const int r4   = lhi * 4;            // first D-row (within wave) this lane owns

    // ---- one-time stage: all weights (pre-swizzled bf16) + biases ----
    for (int i4 = t; i4 < 2560; i4 += 512)
        ((float4*)sh)[i4] = ((const float4*)wbf)[i4];
    if (t < 64)              { sB1[t] = b1[t]; sB2[t] = b2[t]; sB3[t] = b3[t]; }
    if (t >= 64 && t < 192)  sBkv[t - 64] = bkv[t - 64];
    __syncthreads();                     // the ONLY block-wide barrier

    const int srow = lane >> 4;          // 0..3 (row-within-quad for staging)
    const int scol = (lane & 15) << 2;   // float col for staging

    for (int tile = blockIdx.x; tile < ntiles; tile += gridDim.x) {
        const int base  = tile * 128;
        const int ebase = base + rowBase;    // this wave's 16 sorted positions

        // ---- per-wave stage: 16 sorted edges' escal rows -> sA0 (bf16, swz)
#pragma unroll
        for (int p = 0; p < 4; ++p) {
            const int row = p * 4 + srow;                 // 0..15 within wave
            const int er  = perm[ebase + row];            // broadcast per 16 lanes
            const float4 g = *(const float4*)&escal[(size_t)er * 64 + scol];
            ushort4v pk = { f2bf(g.x), f2bf(g.y), f2bf(g.z), f2bf(g.w) };
            *(ushort4v*)&sA0[swz(rowBase + row, scol)] = pk;
        }

        // ---- per-lane metadata for this lane's 4 sorted rows ----
        int   eids[4], gsrc[4], gdst[4];
        float gea[4];
#pragma unroll
        for (int r = 0; r < 4; ++r) eids[r] = perm[ebase + r4 + r];
#pragma unroll
        for (int r = 0; r < 4; ++r) {
            gsrc[r] = esrc[eids[r]];
            gdst[r] = edst[eids[r]];
            gea[r]  = eattr[eids[r]];
        }
        // hoisted q gather (near-uniform rows after sort -> L1 hits)
        float qreg[4][4];
#pragma unroll
        for (int h = 0; h < 4; ++h)
#pragma unroll
            for (int r = 0; r < 4; ++r)
                qreg[h][r] = qbuf[(size_t)gdst[r] * 64 + h * 16 + l15];

        PHASE_FENCE();

        // ================= Layer 1: silu(es@W1+b1) : sA0 -> sA1 =============
        {
            f32x4 acc[4] = {{0,0,0,0},{0,0,0,0},{0,0,0,0},{0,0,0,0}};
#pragma unroll
            for (int kk = 0; kk < 2; ++kk) {
                const bf16x8 a = ldfrag(sA0, rowBase + l15, kk, lhi);
#pragma unroll
                for (int c = 0; c < 4; ++c) {
                    const bf16x8 b = ldfrag(sW1t, c * 16 + l15, kk, lhi);
                    acc[c] = __builtin_amdgcn_mfma_f32_16x16x32_bf16(a, b, acc[c], 0, 0, 0);
                }
            }
#pragma unroll
            for (int c = 0; c < 4; ++c)
#pragma unroll
                for (int r = 0; r < 4; ++r) {
                    const int row = rowBase + r4 + r;
                    const int col = c * 16 + l15;
                    const float v = acc[c][r] + sB1[col];
                    sA1[swz(row, col)] = f2bf(v / (1.f + __expf(-v)));
                }
        }
        PHASE_FENCE();

        // ================= Layer 2: silu(h1@W2+b2) : sA1 -> sA0 =============
        {
            f32x4 acc[4] = {{0,0,0,0},{0,0,0,0},{0,0,0,0},{0,0,0,0}};
#pragma unroll
            for (int kk = 0; kk < 2; ++kk) {
                const bf16x8 a = ldfrag(sA1, rowBase + l15, kk, lhi);
#pragma unroll
                for (int c = 0; c < 4; ++c) {
                    const bf16x8 b = ldfrag(sW2t, c * 16 + l15, kk, lhi);
                    acc[c] = __builtin_amdgcn_mfma_f32_16x16x32_bf16(a, b, acc[c], 0, 0, 0);
                }
            }
#pragma unroll
            for (int c = 0; c < 4; ++c)
#pragma unroll
                for (int r = 0; r < 4; ++r) {
                    const int row = rowBase + r4 + r;
                    const int col = c * 16 + l15;
                    const float v = acc[c][r] + sB2[col];
                    sA0[swz(row, col)] = f2bf(v / (1.f + __expf(-v)));
                }
        }
        PHASE_FENCE();

        // ===== Layer 3 + tp: w = h2@W3+b3; tp=(msrc[s]+mdst[d])*ea*w ========
        {
            f32x4 acc[4] = {{0,0,0,0},{0,0,0,0},{0,0,0,0},{0,0,0,0}};
#pragma unroll
            for (int kk = 0; kk < 2; ++kk) {
                const bf16x8 a = ldfrag(sA0, rowBase + l15, kk, lhi);
#pragma unroll
                for (int c = 0; c < 4; ++c) {
                    const bf16x8 b = ldfrag(sW3t, c * 16 + l15, kk, lhi);
                    acc[c] = __builtin_amdgcn_mfma_f32_16x16x32_bf16(a, b, acc[c], 0, 0, 0);
                }
            }
            float ms[4][4], md[4][4];
#pragma unroll
            for (int c = 0; c < 4; ++c)
#pragma unroll
                for (int r = 0; r < 4; ++r) {
                    const int col = c * 16 + l15;
                    ms[c][r] = msrc[(size_t)gsrc[r] * 64 + col];
                    md[c][r] = mdst[(size_t)gdst[r] * 64 + col];
                }
#pragma unroll
            for (int c = 0; c < 4; ++c)
#pragma unroll
                for (int r = 0; r < 4; ++r) {
                    const int row = rowBase + r4 + r;
                    const int col = c * 16 + l15;
                    const float w  = acc[c][r] + sB3[col];
                    const float tp = (ms[c][r] + md[c][r]) * gea[r] * w;
                    sA1[swz(row, col)] = f2bf(tp);
                }
        }
        PHASE_FENCE();

        // ============ kv2 = tp@Wkv (+bkv): k cols 0..63, v cols 64..127 =====
        f32x4 acc2[8] = {{0,0,0,0},{0,0,0,0},{0,0,0,0},{0,0,0,0},
                         {0,0,0,0},{0,0,0,0},{0,0,0,0},{0,0,0,0}};
#pragma unroll
        for (int kk = 0; kk < 2; ++kk) {
            const bf16x8 a = ldfrag(sA1, rowBase + l15, kk, lhi);
#pragma unroll
            for (int c = 0; c < 8; ++c) {
                const bf16x8 b = ldfrag(sWkvt, c * 16 + l15, kk, lhi);
                acc2[c] = __builtin_amdgcn_mfma_f32_16x16x32_bf16(a, b, acc2[c], 0, 0, 0);
            }
        }

        // ================= alpha, exp, MERGED segmented atomics =============
        float ex[4][4];
        float dh[4] = {0.f, 0.f, 0.f, 0.f};   // head (=l15) exps per row, l15<4
#pragma unroll
        for (int h = 0; h < 4; ++h)
#pragma unroll
            for (int r = 0; r < 4; ++r) {
                float s = (acc2[h][r] + sBkv[h * 16 + l15]) * qreg[h][r];
                s += __shfl_xor(s, 1);
                s += __shfl_xor(s, 2);
                s += __shfl_xor(s, 4);
                s += __shfl_xor(s, 8);
                const float e = __expf(s);
                ex[h][r] = e;
                if (l15 == h) dh[r] = e;
            }

        // den: lanes l15<4 own head l15; merge equal-dst runs over r
        if (l15 < 4) {
            float accd = 0.f;
#pragma unroll
            for (int r = 0; r < 4; ++r) {
                accd += dh[r];
                if (r == 3 || gdst[r + 1] != gdst[r]) {
                    atomicAdd(&den[(size_t)gdst[r] * 4 + l15], accd);
                    accd = 0.f;
                }
            }
        }

        // num: merge equal-dst runs over r before atomic emit
#pragma unroll
        for (int vt = 0; vt < 4; ++vt) {
            float accv = 0.f;
#pragma unroll
            for (int r = 0; r < 4; ++r) {
                accv += ex[vt][r] * (acc2[4 + vt][r] + sBkv[64 + vt * 16 + l15]);
                if (r == 3 || gdst[r + 1] != gdst[r]) {
                    atomicAdd(&num[(size_t)gdst[r] * 64 + vt * 16 + l15], accv);
                    accv = 0.f;
                }
            }
        }

        PHASE_FENCE();
    }
}

// ---------------------------------------------------------------------------
// Kernel C: out = (num/(den+1e-16)) @ W_proj + b_proj, persistent (unchanged).
// ---------------------------------------------------------------------------
__global__ __launch_bounds__(256)
void final_proj_kernel(const float* __restrict__ num, const float* __restrict__ den,
                       const float* __restrict__ Wp, const float* __restrict__ bp,
                       float* __restrict__ out, int N, int ntiles)
{
    __shared__ __align__(16) float sW[64 * 64];
    __shared__ float sb[64];
    __shared__ __align__(16) float at[64][68];

    const int t = threadIdx.x;
    for (int i4 = t; i4 < 1024; i4 += 256)
        ((float4*)sW)[i4] = ((const float4*)Wp)[i4];
    if (t < 64) sb[t] = bp[t];

    const int te = t >> 4, tj = t & 15;
    const int j0 = tj * 4, e0 = te * 4;

    for (int tile = blockIdx.x; tile < ntiles; tile += gridDim.x) {
        const int nbase = tile * 64;
        __syncthreads();
        for (int idx = t; idx < 1024; idx += 256) {
            const int n  = idx >> 4;
            const int c4 = (idx & 15) * 4;
            const int gn = nbase + n;
            float4 g = make_float4(0.f, 0.f, 0.f, 0.f);
            if (gn < N) {
                const float4 nm = *(const float4*)&num[(size_t)gn * 64 + c4];
                const float inv = 1.0f / (den[(size_t)gn * 4 + (c4 >> 4)] + 1e-16f);
                g = make_float4(nm.x * inv, nm.y * inv, nm.z * inv, nm.w * inv);
            }
            *(float4*)&at[n][c4] = g;
        }
        __syncthreads();

        float acc[4][4];
#pragma unroll
        for (int i = 0; i < 4; ++i)
#pragma unroll
            for (int c = 0; c < 4; ++c) acc[i][c] = 0.f;

#pragma unroll 16
        for (int k = 0; k < 64; ++k) {
            const float4 wv = *(const float4*)&sW[k * 64 + j0];
            const float a0 = at[e0 + 0][k], a1 = at[e0 + 1][k];
            const float a2 = at[e0 + 2][k], a3 = at[e0 + 3][k];
            acc[0][0] += a0 * wv.x; acc[0][1] += a0 * wv.y; acc[0][2] += a0 * wv.z; acc[0][3] += a0 * wv.w;
            acc[1][0] += a1 * wv.x; acc[1][1] += a1 * wv.y; acc[1][2] += a1 * wv.z; acc[1][3] += a1 * wv.w;
            acc[2][0] += a2 * wv.x; acc[2][1] += a2 * wv.y; acc[2][2] += a2 * wv.z; acc[2][3] += a2 * wv.w;
            acc[3][0] += a3 * wv.x; acc[3][1] += a3 * wv.y; acc[3][2] += a3 * wv.z; acc[3][3] += a3 * wv.w;
        }

#pragma unroll
        for (int i = 0; i < 4; ++i) {
            const int gn = nbase + e0 + i;
            if (gn >= N) continue;
            float4 o;
            o.x = acc[i][0] + sb[j0 + 0];
            o.y = acc[i][1] + sb[j0 + 1];
            o.z = acc[i][2] + sb[j0 + 2];
            o.w = acc[i][3] + sb[j0 + 3];
            *(float4*)&out[(size_t)gn * 64 + j0] = o;
        }
    }
}

// ---------------------------------------------------------------------------
extern "C" void kernel_launch(void* const* d_in, const int* in_sizes, int n_in,
                              void* d_out, int out_size, void* d_ws, size_t ws_size,
                              hipStream_t stream)
{
    const float* node_input = (const float*)d_in[0];
    const int*   edge_src   = (const int*)  d_in[2];
    const int*   edge_dst   = (const int*)  d_in[3];
    const float* edge_attr  = (const float*)d_in[4];
    const float* edge_scal  = (const float*)d_in[5];
    const float* Wq    = (const float*)d_in[7];
    const float* bq    = (const float*)d_in[8];
    const float* W_src = (const float*)d_in[9];
    const float* b_src = (const float*)d_in[10];
    const float* W_dst = (const float*)d_in[11];
    const float* W_fc1 = (const float*)d_in[12];
    const float* b_fc1 = (const float*)d_in[13];
    const float* W_fc2 = (const float*)d_in[14];
    const float* b_fc2 = (const float*)d_in[15];
    const float* W_fc3 = (const float*)d_in[16];
    const float* b_fc3 = (const float*)d_in[17];
    const float* W_kv  = (const float*)d_in[18];
    const float* b_kv  = (const float*)d_in[19];
    const float* W_proj = (const float*)d_in[20];
    const float* b_proj = (const float*)d_in[21];

    const int N = in_sizes[0] / 64;    // 50000
    const int E = in_sizes[2];         // 800000

    float* ws    = (float*)d_ws;
    float* q_buf = ws;                                   // N*64
    float* msrc  = ws + (size_t)N * 64;                  // N*64
    float* mdst  = ws + (size_t)N * 128;                 // N*64
    float* num   = ws + (size_t)N * 192;                 // N*64
    float* den   = ws + (size_t)N * 256;                 // N*4
    unsigned short* wbf = (unsigned short*)(ws + (size_t)N * 260);  // 20480 ushort = 10240 floats
    int* cnt    = (int*)(ws + (size_t)N * 260 + 10240);  // N ints
    int* cursor = cnt + N;                               // N ints
    int* perm   = cursor + N;                            // E ints

    hipMemsetAsync(num, 0, (size_t)N * 68 * sizeof(float), stream);
    hipMemsetAsync(cnt, 0, (size_t)N * sizeof(int), stream);

    // one-time bf16 pre-swizzled weight images
    prep_weights<<<80, 256, 0, stream>>>(W_fc1, W_fc2, W_fc3, W_kv, wbf);

    // counting sort by dst -> perm
    hist_kernel<<<(E + 255) / 256, 256, 0, stream>>>(edge_dst, cnt, E);
    scan_kernel<<<1, 1024, 0, stream>>>(cnt, cursor, N);
    rank_kernel<<<(E + 255) / 256, 256, 0, stream>>>(edge_dst, cursor, perm, E);

    {
        const int ntiles = (N + 31) / 32;     // 1563
        node_linear_kernel<<<512, 384, 0, stream>>>(node_input, Wq, bq, W_src, b_src, W_dst,
                                                    q_buf, msrc, mdst, N, ntiles);
    }
    {
        const int ntiles = E / 128;           // 6250
        edge_fused_mfma<<<512, 512, 0, stream>>>(edge_src, edge_dst, edge_attr, edge_scal,
                                                 perm, wbf, b_fc1, b_fc2, b_fc3, b_kv,
                                                 q_buf, msrc, mdst, num, den, ntiles);
    }
    {
        const int ntiles = (N + 63) / 64;     // 782
        final_proj_kernel<<<512, 256, 0, stream>>>(num, den, W_proj, b_proj,
                                                   (float*)d_out, N, ntiles);
    }
}